// Round 1
// 2541.307 us; speedup vs baseline: 1.3211x; 1.3211x over previous
//
#include <hip/hip_runtime.h>
#include <stdint.h>
#include <math.h>

// Problem constants (fixed by the reference)
#define NSAMP 262144
#define NSTEPS 50
#define US_OFF   26738688ull   // 51*N*2
#define TIMES_OFF 52953088ull  // US_OFF + 50*N*2

static constexpr float LOG2E_F = 1.4426950408889634f;
static constexpr float LN2_F   = 0.6931471805599453f;

typedef __attribute__((ext_vector_type(8))) short bf16x8;
typedef __attribute__((ext_vector_type(4))) float f32x4;

struct U4 { uint32_t x, y, z, w; };

__device__ __forceinline__ uint16_t bf16_rne(float f) {
  uint32_t u = __builtin_bit_cast(uint32_t, f);
  u += 0x7FFFu + ((u >> 16) & 1u);
  return (uint16_t)(u >> 16);
}
__device__ __forceinline__ uint32_t packpair_rne(float a, float b) {
  return (uint32_t)bf16_rne(a) | ((uint32_t)bf16_rne(b) << 16);
}
// hot pack: truncate both f32 to bf16 in one v_perm_b32 (lo -> low half)
__device__ __forceinline__ uint32_t pack2_trunc(float lo, float hi) {
  return __builtin_amdgcn_perm(__builtin_bit_cast(uint32_t, hi),
                               __builtin_bit_cast(uint32_t, lo), 0x07060302u);
}
// y = log2e*x ; returns log2e*silu(x) = y / (1 + 2^-y)
__device__ __forceinline__ float silu_s(float y) {
  float e = __builtin_amdgcn_exp2f(-y);
  return y * __builtin_amdgcn_rcpf(1.0f + e);
}
__device__ __forceinline__ float sel4(float a0, float a1, float a2, float a3, int r) {
  float v = a0;
  v = (r == 1) ? a1 : v;
  v = (r == 2) ? a2 : v;
  v = (r == 3) ? a3 : v;
  return v;
}

// DPP rotation-based sum over each row of 16 lanes (replaces shfl_xor butterfly:
// ds_swizzle on the LDS pipe -> v_add_f32_dpp on the VALU). Sum only — order of
// pairing is irrelevant: quad swaps give quad sums, row_ror:4 adds the adjacent
// quad, row_ror:8 adds the remaining two. All 16 lanes end with the full sum.
#define DPP_ADD(v, ctrl) ((v) + __builtin_bit_cast(float, \
    __builtin_amdgcn_update_dpp(0, __builtin_bit_cast(int, (v)), (ctrl), 0xF, 0xF, true)))
__device__ __forceinline__ float red16(float v) {
  v = DPP_ADD(v, 0xB1);   // quad_perm [1,0,3,2]
  v = DPP_ADD(v, 0x4E);   // quad_perm [2,3,0,1]
  v = DPP_ADD(v, 0x124);  // row_ror:4
  v = DPP_ADD(v, 0x128);  // row_ror:8
  return v;
}

// Stage a 128x128 row-major [k][n] fp32 matrix into MFMA B-frag layout (bf16):
// frag linear idx = ((kt*8+ct)*64 + lane)*8 + j, lane = q*16 + (n&15), k = kt*32+q*8+j
__device__ __forceinline__ void stage_frags(uint16_t* frag, const float* __restrict__ W,
                                            float scale, int tid) {
  for (int e = tid; e < 16384; e += 512) {
    int k = e >> 7, n = e & 127;
    int idx = ((((k >> 5) << 3) | (n >> 4)) << 9) |
              (((((k >> 3) & 3) << 4) | (n & 15)) << 3) | (k & 7);
    frag[idx] = bf16_rne(W[e] * scale);
  }
}

// ---------------- prep: per-step fourier/bias vectors + scalars + times ----------------
__global__ void sde_prep_kernel(const float* __restrict__ times, const float* __restrict__ freqs,
                                const float* __restrict__ dW1, const float* __restrict__ db1,
                                const float* __restrict__ cW1, const float* __restrict__ cb1,
                                const float* __restrict__ log_diff,
                                float* __restrict__ wsF, float* __restrict__ out) {
  int i = blockIdx.x;          // 0..50
  int t = threadIdx.x;         // 256
  if (t == 0) out[TIMES_OFF + i] = times[i];
  if (i >= NSTEPS) return;
  float ti = times[i];
  int net = t >> 7, k = t & 127;           // net 0 = c (cnf), net 1 = d (posterior)
  const float* W1 = net ? dW1 : cW1;
  const float* b1 = net ? db1 : cb1;
  float acc = b1[k];
  for (int f = 0; f < 16; ++f) {
    float arg = 6.283185307179586f * ti * freqs[f];
    float sv = sinf(arg), cv = cosf(arg);
    acc += sv * W1[(130 + f) * 128 + k] + cv * W1[(146 + f) * 128 + k];
  }
  wsF[i * 256 + net * 128 + k] = acc * LOG2E_F;   // \hat At (b1 folded, log2e-scaled)
  if (t == 0) {
    float dt = times[i + 1] - times[i];
    wsF[12800 + i] = dt;
    float ld = log_diff[0];
    float gb = (ld > 20.f) ? ld : log1pf(expf(ld));   // softplus * DIFFUSION_SCALE(=1)
    wsF[12850 + i] = gb * (1.0f - ti) * sqrtf(fmaxf(dt, 1e-12f));
  }
}

// ---------------- main fused 50-step kernel ----------------
// block = 512 thr (8 waves). waves 0-3: cnf-net(f), waves 4-7: posterior-net(u).
// Each wave owns 16 samples (M=16 MFMA tile). 64 samples / block, grid = 4096.
//
// v2: W2 B-frags live in LDS (both nets, 64 KB) instead of 128 regs/wave of
// AGPR — combined register file per wave drops from ~256 to ~110, so TWO
// blocks fit per CU (4 waves/SIMD) instead of one. The 64 KB region is a
// union: phase-A W1 staging (32 KB) + bf16 transpose buffer (17 KB) live
// there before the W2 frags are staged. __launch_bounds__(512,4) pins the
// register target at 128.
__global__ __launch_bounds__(512, 4) void sde_main_kernel(
    const float* __restrict__ z0, const float* __restrict__ post_ctx,
    const float* __restrict__ cnf_ctx, const float* __restrict__ noise,
    const float* __restrict__ dW1, const float* __restrict__ dW2,
    const float* __restrict__ dW3, const float* __restrict__ db3,
    const float* __restrict__ cW1, const float* __restrict__ cW2,
    const float* __restrict__ cW3, const float* __restrict__ cb3,
    const float* __restrict__ db2v, const float* __restrict__ cb2v,
    const float* __restrict__ wsF, float* __restrict__ out) {

  // 64 KB union:
  //   phase A : [0,32768)  W1[2:130] B-frag staging (bf16)
  //             [32768,50176) transpose buffer [4][16][136] uint16
  //   steady  : [0,32768)  cnf-net W2 frags ; [32768,65536) posterior-net W2 frags
  __shared__ __align__(16) unsigned char ldsU[65536];
  __shared__ float ldsW1z[2][2][128];                        // 2 KB: log2e*W1 rows 0,1
  __shared__ float ldsSb2[2][128];                           // 1 KB: log2e*b2
  __shared__ float ldsW3[2][128][2];                         // 2 KB: ln2*W3
  __shared__ float ldsFU[2][2][64][2];                       // 2 KB: [parity][f/u][ls][j]

  uint16_t* fragS = (uint16_t*)ldsU;
  uint16_t* ldsTp = (uint16_t*)(ldsU + 32768);               // [wsub*2176 + row*136 + col]

  const int tid  = threadIdx.x;
  const int wave = tid >> 6, lane = tid & 63;
  const int q = lane >> 4, c = lane & 15;
  const int grp = wave >> 2;        // 0 = cnf(f), 1 = posterior(u)
  const int wsub = wave & 3;
  const int ls = wsub * 16 + c;     // block-local sample
  const size_t s = (size_t)blockIdx.x * 64 + ls;

  // small stagings (covered by the first __syncthreads below)
  { int nn = tid >> 8, row = (tid >> 7) & 1, k = tid & 127;
    const float* W1 = nn ? dW1 : cW1;
    ldsW1z[nn][row][k] = W1[row * 128 + k] * LOG2E_F; }
  if (tid < 256) { int nn = tid >> 7, k = tid & 127;
    const float* b2 = nn ? db2v : cb2v;
    ldsSb2[nn][k] = b2[k] * LOG2E_F; }
  { int nn = tid >> 8, r2 = tid & 255, k = r2 >> 1, j = r2 & 1;
    const float* W3 = nn ? dW3 : cW3;
    ldsW3[nn][k][j] = W3[k * 2 + j] * LN2_F; }

  // ---- Phase A: Creg = log2e * (ctx @ W1[2:130])  (bf16 A-frags in registers) ----
  U4 crg[4];
  for (int net = 0; net < 2; ++net) {
    stage_frags(fragS, (net ? dW1 : cW1) + 256, LOG2E_F, tid);
    __syncthreads();
    if (grp == net) {
      const float* ctxP = net ? post_ctx : cnf_ctx;
      U4 afr[4];
      #pragma unroll
      for (int kt = 0; kt < 4; ++kt) {
        const float4* cp = (const float4*)(ctxP + ((size_t)blockIdx.x * 64 + wsub * 16 + c) * 128
                                           + kt * 32 + q * 8);
        float4 a0 = cp[0], a1 = cp[1];
        afr[kt] = U4{packpair_rne(a0.x, a0.y), packpair_rne(a0.z, a0.w),
                     packpair_rne(a1.x, a1.y), packpair_rne(a1.z, a1.w)};
      }
      #pragma unroll
      for (int ct = 0; ct < 8; ++ct) {
        f32x4 acc = {0.f, 0.f, 0.f, 0.f};
        #pragma unroll
        for (int kt = 0; kt < 4; ++kt)
          acc = __builtin_amdgcn_mfma_f32_16x16x32_bf16(
              __builtin_bit_cast(bf16x8, afr[kt]),
              *(const bf16x8*)&fragS[((kt * 8 + ct) << 9) + (lane << 3)], acc, 0, 0, 0);
        #pragma unroll
        for (int r = 0; r < 4; ++r)
          ldsTp[wsub * 2176 + (q * 4 + r) * 136 + ct * 16 + c] = bf16_rne(acc[r]);
      }
      asm volatile("s_waitcnt lgkmcnt(0)" ::: "memory");
      #pragma unroll
      for (int kt = 0; kt < 4; ++kt)
        crg[kt] = *(const U4*)&ldsTp[wsub * 2176 + c * 136 + kt * 32 + q * 8];
    }
    __syncthreads();
  }

  // ---- Phase B: stage BOTH nets' W2 B-frags into LDS (resident for the loop) ----
  for (int e = tid; e < 32768; e += 512) {
    int nn = e >> 14, rr = e & 16383;
    int k = rr >> 7, n = rr & 127;
    int idx = (nn << 14) | ((((k >> 5) << 3) | (n >> 4)) << 9) |
              (((((k >> 3) & 3) << 4) | (n & 15)) << 3) | (k & 7);
    fragS[idx] = bf16_rne((nn ? dW2 : cW2)[rr]);
  }
  __syncthreads();

  const float* b3p = grp ? db3 : cb3;
  const float b3x = b3p[0], b3y = b3p[1];

  // z state (every lane tracks z of its own sample ls)
  float zx = z0[s * 2], zy = z0[s * 2 + 1];
  const bool writer = ((c >> 2) == q);
  const int r_w = c & 3;
  if (grp == 0 && writer) { float2 v{zx, zy}; *(float2*)&out[s * 2] = v; }  // traj[0]

  const uint16_t* wbase = fragS + (grp << 14) + (lane << 3);   // this net's W2 frags

  // ---- 50-step loop ----
  for (int i = 0; i < NSTEPS; ++i) {
    const float dt  = wsF[12800 + i];
    const float gns = wsF[12850 + i];

    // layer1 + silu -> bf16 A-frags
    U4 hfr[4];
    #pragma unroll
    for (int kt = 0; kt < 4; ++kt) {
      const float4* w0p = (const float4*)&ldsW1z[grp][0][kt * 32 + q * 8];
      const float4* w1p = (const float4*)&ldsW1z[grp][1][kt * 32 + q * 8];
      float4 w0a = w0p[0], w0b = w0p[1], w1a = w1p[0], w1b = w1p[1];
      const float4* atp = (const float4*)(wsF + i * 256 + grp * 128 + kt * 32 + q * 8);
      float4 ata = atp[0], atb = atp[1];
      auto pairf = [&](uint32_t cu, float atL, float atH, float w0L, float w0H,
                       float w1L, float w1H) -> uint32_t {
        float cL = __builtin_bit_cast(float, cu << 16);
        float cH = __builtin_bit_cast(float, cu & 0xFFFF0000u);
        float yL = fmaf(zx, w0L, fmaf(zy, w1L, cL + atL));
        float yH = fmaf(zx, w0H, fmaf(zy, w1H, cH + atH));
        return pack2_trunc(silu_s(yL), silu_s(yH));
      };
      hfr[kt] = U4{pairf(crg[kt].x, ata.x, ata.y, w0a.x, w0a.y, w1a.x, w1a.y),
                   pairf(crg[kt].y, ata.z, ata.w, w0a.z, w0a.w, w1a.z, w1a.w),
                   pairf(crg[kt].z, atb.x, atb.y, w0b.x, w0b.y, w1b.x, w1b.y),
                   pairf(crg[kt].w, atb.z, atb.w, w0b.z, w0b.w, w1b.z, w1b.w)};
    }

    // layer2 MFMA (B-frags streamed from LDS, b2 folded into acc init)
    // + silu + layer3 partials
    float p00 = 0.f, p01 = 0.f, p02 = 0.f, p03 = 0.f;
    float p10 = 0.f, p11 = 0.f, p12 = 0.f, p13 = 0.f;
    #pragma unroll
    for (int ct = 0; ct < 8; ++ct) {
      float sb  = ldsSb2[grp][ct * 16 + c];
      f32x4 acc = {sb, sb, sb, sb};
      #pragma unroll
      for (int kt = 0; kt < 4; ++kt)
        acc = __builtin_amdgcn_mfma_f32_16x16x32_bf16(
            __builtin_bit_cast(bf16x8, hfr[kt]),
            *(const bf16x8*)(wbase + ((kt * 8 + ct) << 9)), acc, 0, 0, 0);
      float w30 = ldsW3[grp][ct * 16 + c][0];
      float w31 = ldsW3[grp][ct * 16 + c][1];
      float h0 = silu_s(acc[0]), h1 = silu_s(acc[1]);
      float h2 = silu_s(acc[2]), h3 = silu_s(acc[3]);
      p00 = fmaf(h0, w30, p00); p10 = fmaf(h0, w31, p10);
      p01 = fmaf(h1, w30, p01); p11 = fmaf(h1, w31, p11);
      p02 = fmaf(h2, w30, p02); p12 = fmaf(h2, w31, p12);
      p03 = fmaf(h3, w30, p03); p13 = fmaf(h3, w31, p13);
    }
    // sum over the 16 lanes of each row-of-16 (VALU DPP, no LDS pipe)
    p00 = red16(p00); p10 = red16(p10);
    p01 = red16(p01); p11 = red16(p11);
    p02 = red16(p02); p12 = red16(p12);
    p03 = red16(p03); p13 = red16(p13);
    p00 += b3x; p01 += b3x; p02 += b3x; p03 += b3x;
    p10 += b3y; p11 += b3y; p12 += b3y; p13 += b3y;

    if (writer) {
      float vx = sel4(p00, p01, p02, p03, r_w);
      float vy = sel4(p10, p11, p12, p13, r_w);
      float2 v{vx, vy};
      *(float2*)&ldsFU[i & 1][grp][ls][0] = v;
      if (grp == 1) *(float2*)&out[US_OFF + ((size_t)i * NSAMP + s) * 2] = v;  // us = u
    }
    __syncthreads();

    float2 fv = *(const float2*)&ldsFU[i & 1][0][ls][0];
    float2 uv = *(const float2*)&ldsFU[i & 1][1][ls][0];
    float nx = noise[((size_t)i * NSAMP + s) * 2];
    float ny = noise[((size_t)i * NSAMP + s) * 2 + 1];
    zx = fmaf(fv.x + uv.x, dt, fmaf(nx, gns, zx));
    zy = fmaf(fv.y + uv.y, dt, fmaf(ny, gns, zy));
    if (grp == 0 && writer) {
      float2 v{zx, zy};
      *(float2*)&out[((size_t)(i + 1) * NSAMP + s) * 2] = v;   // traj[i+1]
    }
  }
}

extern "C" void kernel_launch(void* const* d_in, const int* in_sizes, int n_in,
                              void* d_out, int out_size, void* d_ws, size_t ws_size,
                              hipStream_t stream) {
  const float* z0    = (const float*)d_in[0];
  const float* post  = (const float*)d_in[1];
  const float* cnf   = (const float*)d_in[2];
  const float* times = (const float*)d_in[3];
  const float* noise = (const float*)d_in[4];
  const float* freqs = (const float*)d_in[5];
  const float* dW1 = (const float*)d_in[6];  const float* db1 = (const float*)d_in[7];
  const float* dW2 = (const float*)d_in[8];  const float* db2 = (const float*)d_in[9];
  const float* dW3 = (const float*)d_in[10]; const float* db3 = (const float*)d_in[11];
  const float* cW1 = (const float*)d_in[12]; const float* cb1 = (const float*)d_in[13];
  const float* cW2 = (const float*)d_in[14]; const float* cb2 = (const float*)d_in[15];
  const float* cW3 = (const float*)d_in[16]; const float* cb3 = (const float*)d_in[17];
  const float* logd = (const float*)d_in[18];
  float* out = (float*)d_out;
  float* wsF = (float*)d_ws;

  sde_prep_kernel<<<51, 256, 0, stream>>>(times, freqs, dW1, db1, cW1, cb1, logd, wsF, out);
  sde_main_kernel<<<4096, 512, 0, stream>>>(z0, post, cnf, noise,
                                            dW1, dW2, dW3, db3,
                                            cW1, cW2, cW3, cb3,
                                            db2, cb2, wsF, out);
}